// Round 8
// baseline (171.114 us; speedup 1.0000x reference)
//
#include <hip/hip_runtime.h>
#include <hip/hip_bf16.h>
#include <stdint.h>

#define B_ 4
#define S_ 2048
#define E_ 1024
#define H_ 16
#define D_ 64
#define BS_ (B_*S_)     // 8192
#define N1_ (3*E_)      // 3072

typedef __attribute__((ext_vector_type(4))) float f32x4;
typedef __attribute__((ext_vector_type(16))) float f32x16;
typedef __attribute__((ext_vector_type(8))) short bf16x8;

#define QSCL 0.18033688011112043f   // 0.125 * log2(e), folded into Q at gemm1

__device__ __forceinline__ float expraw(float x) {   // 2^x, no OCML fixup
  float r;
  asm("v_exp_f32 %0, %1" : "=v"(r) : "v"(x));
  return r;
}

__device__ __forceinline__ unsigned short f2bf(float f) {
  union { float f; unsigned u; } v; v.f = f;
  unsigned r = v.u + 0x7fffu + ((v.u >> 16) & 1u);  // RNE
  return (unsigned short)(r >> 16);
}

__device__ __forceinline__ void gload_lds16(const void* g, void* l) {
  __builtin_amdgcn_global_load_lds(
      (const __attribute__((address_space(1))) void*)g,
      (__attribute__((address_space(3))) void*)l, 16, 0, 0);
}

// ---------------- x: f32 -> bf16, vectorized ----------------
__global__ void k_cvt_x(const float* __restrict__ in, unsigned short* __restrict__ out, int n4) {
  int i = blockIdx.x * blockDim.x + threadIdx.x;
  int stride = gridDim.x * blockDim.x;
  for (; i < n4; i += stride) {
    float4 v = ((const float4*)in)[i];
    ushort4 o;
    o.x = f2bf(v.x); o.y = f2bf(v.y); o.z = f2bf(v.z); o.w = f2bf(v.w);
    ((ushort4*)out)[i] = o;
  }
}

// ---------- Wq/Wk/Wv [H][E][D] -> Wt [3*E][E] (B^T layout, bf16) ----------
__global__ void k_wqkv_t(const float* __restrict__ Wq, const float* __restrict__ Wk,
                         const float* __restrict__ Wv, unsigned short* __restrict__ Wt) {
  __shared__ float t[64][65];
  const int et = blockIdx.x, h = blockIdx.y, qkv = blockIdx.z;
  const float* W = (qkv == 0) ? Wq : ((qkv == 1) ? Wk : Wv);
  const int tid = threadIdx.x;
  const int e0 = et * 64;
#pragma unroll
  for (int i = 0; i < 16; ++i) {
    int idx = tid + i * 256;
    int r = idx >> 6, c = idx & 63;
    t[r][c] = W[(size_t)(h * E_ + e0 + r) * D_ + c];
  }
  __syncthreads();
#pragma unroll
  for (int i = 0; i < 16; ++i) {
    int idx = tid + i * 256;
    int d = idx >> 6, j = idx & 63;
    Wt[(size_t)(qkv * E_ + h * D_ + d) * E_ + e0 + j] = f2bf(t[j][d]);
  }
}

// ---------- Wp [E][E] -> Wpt [n][e] bf16 ----------
__global__ void k_wp_t(const float* __restrict__ Wp, unsigned short* __restrict__ Wpt) {
  __shared__ float t[64][65];
  const int ntb = blockIdx.x, etb = blockIdx.y;
  const int tid = threadIdx.x;
  const int n0 = ntb * 64, e0 = etb * 64;
#pragma unroll
  for (int i = 0; i < 16; ++i) {
    int idx = tid + i * 256;
    int r = idx >> 6, c = idx & 63;
    t[r][c] = Wp[(size_t)(e0 + r) * E_ + n0 + c];
  }
  __syncthreads();
#pragma unroll
  for (int i = 0; i < 16; ++i) {
    int idx = tid + i * 256;
    int d = idx >> 6, j = idx & 63;
    Wpt[(size_t)(n0 + d) * E_ + e0 + j] = f2bf(t[j][d]);
  }
}

// ============ 256x256 8-wave 4-phase counted-vmcnt GEMM (m201 port) ============
// 512 thr = 8 waves (2M x 4N); per-wave 128x64 = 8fi x 4fj frags of 16x16x32.
// BK=64 split as 2 kh-planes of K=32. LDS 128 KiB dynamic:
//   buf d (d*32768 shorts) + region r*8192, regions: {A-kh0, B-kh0, A-kh1, B-kh1},
//   each region = [256 rows][32 bf16] (64B rows).
// Swizzle (re-derived, 2 lanes/bank): read slot = l4 ^ ((l16>>1)&3); inverse
// applied to GLOBAL staging source, LDS dest stays linear (rule 21).
// Schedule per K-tile (4 phases): ph reads only its kh's regions; one region of
// buf[c^1] (tile T+1) staged per phase; vmcnt(4) before the trailing barrier of
// odd phases certifies the next kh's regions globally (drain -> barrier).
#define MM16(a, b, c) c = __builtin_amdgcn_mfma_f32_16x16x32_bf16(a, b, c, 0, 0, 0)

template <int EPI>
__global__ __launch_bounds__(512, 2) void k_gemm256(
    const unsigned short* __restrict__ A,   // [M][K] bf16
    const unsigned short* __restrict__ Bt,  // [N][K] bf16
    void* __restrict__ Cv,
    const float* __restrict__ bias,
    int M, int N, int K, int nbm) {
  extern __shared__ short lds[];            // 65536 shorts = 128 KiB
  const int tid = threadIdx.x;
  const int wid = tid >> 6, lane = tid & 63;
  const int l16 = lane & 15, l4 = lane >> 4;
  const int wm = wid >> 2, wn = wid & 3;

  const int nwg = gridDim.x;                // 384 / 128, both % 8 == 0
  const int cpx = nwg >> 3;
  const int wg = ((int)blockIdx.x & 7) * cpx + ((int)blockIdx.x >> 3);
  const int row0 = (wg % nbm) << 8;
  const int col0 = (wg / nbm) << 8;

  // ---- staging source (inverse-swizzled global, linear LDS dest) ----
  const int srow = tid >> 2;                        // 0..127
  const int sk = ((tid & 3) ^ ((tid >> 3) & 3)) * 8;  // swizzled k-chunk (shorts)
  const unsigned short* AsL = A + (size_t)(row0 + srow) * K + sk;
  const unsigned short* AsH = AsL + (size_t)128 * K;
  const unsigned short* BsL = Bt + (size_t)(col0 + srow) * K + sk;
  const unsigned short* BsH = BsL + (size_t)128 * K;
  const int dL = tid * 8, dH = tid * 8 + 4096;      // shorts within region

  // region r of buf n, for K-tile tt, kh plane: src k-offset = tt*64 + kh*32
#define STG(n_, r_, koff_, PL, PH)                               \
  do {                                                           \
    gload_lds16((PL) + (koff_), lds + (n_) * 32768 + (r_) * 8192 + dL); \
    gload_lds16((PH) + (koff_), lds + (n_) * 32768 + (r_) * 8192 + dH); \
  } while (0)

  // ---- read-side (swizzled) ----
  const int rsw = (l4 ^ ((l16 >> 1) & 3)) * 8;      // shorts within 64B row
  const int aRow = wm * 128 + l16;                  // + fi*16
  const int bRow = wn * 64 + l16;                   // + fj*16
#define RDA(c_, kh_, fi_) (*(const bf16x8*)&lds[(c_) * 32768 + (kh_) * 16384 + (aRow + (fi_) * 16) * 32 + rsw])
#define RDB(c_, kh_, fj_) (*(const bf16x8*)&lds[(c_) * 32768 + (kh_) * 16384 + 8192 + (bRow + (fj_) * 16) * 32 + rsw])

  f32x4 acc[8][4] = {};
  const int NT = K >> 6;                            // 16

  // prologue: stage tile 0 -> buf 0 (A0,B0,A1,B1); certify kh0 regions
  STG(0, 0, 0, AsL, AsH);
  STG(0, 1, 0, BsL, BsH);
  STG(0, 2, 32, AsL, AsH);
  STG(0, 3, 32, BsL, BsH);
  asm volatile("s_waitcnt vmcnt(4)" ::: "memory");
  __builtin_amdgcn_s_barrier();

  for (int T = 0; T < NT; ++T) {
    const int c = T & 1, n = c ^ 1;
    const int kn = (T + 1) * 64;                    // next tile's K-base
    const bool st = (T + 1 < NT);
    bf16x8 a0, a1, a2, a3, b0, b1, b2, b3;

    // ---- phase 0: kh0, fi 0-3 ----
    a0 = RDA(c, 0, 0); a1 = RDA(c, 0, 1); a2 = RDA(c, 0, 2); a3 = RDA(c, 0, 3);
    b0 = RDB(c, 0, 0); b1 = RDB(c, 0, 1); b2 = RDB(c, 0, 2); b3 = RDB(c, 0, 3);
    if (st) STG(n, 0, kn, AsL, AsH);
    __builtin_amdgcn_s_barrier();
    __builtin_amdgcn_s_setprio(1);
    MM16(a0, b0, acc[0][0]); MM16(a0, b1, acc[0][1]); MM16(a0, b2, acc[0][2]); MM16(a0, b3, acc[0][3]);
    MM16(a1, b0, acc[1][0]); MM16(a1, b1, acc[1][1]); MM16(a1, b2, acc[1][2]); MM16(a1, b3, acc[1][3]);
    MM16(a2, b0, acc[2][0]); MM16(a2, b1, acc[2][1]); MM16(a2, b2, acc[2][2]); MM16(a2, b3, acc[2][3]);
    MM16(a3, b0, acc[3][0]); MM16(a3, b1, acc[3][1]); MM16(a3, b2, acc[3][2]); MM16(a3, b3, acc[3][3]);
    __builtin_amdgcn_s_setprio(0);
    __builtin_amdgcn_s_barrier();

    // ---- phase 1: kh0, fi 4-7 (b0-3 reused from regs) ----
    a0 = RDA(c, 0, 4); a1 = RDA(c, 0, 5); a2 = RDA(c, 0, 6); a3 = RDA(c, 0, 7);
    if (st) STG(n, 1, kn, BsL, BsH);
    __builtin_amdgcn_s_barrier();
    __builtin_amdgcn_s_setprio(1);
    MM16(a0, b0, acc[4][0]); MM16(a0, b1, acc[4][1]); MM16(a0, b2, acc[4][2]); MM16(a0, b3, acc[4][3]);
    MM16(a1, b0, acc[5][0]); MM16(a1, b1, acc[5][1]); MM16(a1, b2, acc[5][2]); MM16(a1, b3, acc[5][3]);
    MM16(a2, b0, acc[6][0]); MM16(a2, b1, acc[6][1]); MM16(a2, b2, acc[6][2]); MM16(a2, b3, acc[6][3]);
    MM16(a3, b0, acc[7][0]); MM16(a3, b1, acc[7][1]); MM16(a3, b2, acc[7][2]); MM16(a3, b3, acc[7][3]);
    __builtin_amdgcn_s_setprio(0);
    if (st) { asm volatile("s_waitcnt vmcnt(4)" ::: "memory"); }
    else    { asm volatile("s_waitcnt vmcnt(0)" ::: "memory"); }
    __builtin_amdgcn_s_barrier();                   // kh1 regions certified

    // ---- phase 2: kh1, fi 0-3 ----
    a0 = RDA(c, 1, 0); a1 = RDA(c, 1, 1); a2 = RDA(c, 1, 2); a3 = RDA(c, 1, 3);
    b0 = RDB(c, 1, 0); b1 = RDB(c, 1, 1); b2 = RDB(c, 1, 2); b3 = RDB(c, 1, 3);
    if (st) STG(n, 2, kn + 32, AsL, AsH);
    __builtin_amdgcn_s_barrier();
    __builtin_amdgcn_s_setprio(1);
    MM16(a0, b0, acc[0][0]); MM16(a0, b1, acc[0][1]); MM16(a0, b2, acc[0][2]); MM16(a0, b3, acc[0][3]);
    MM16(a1, b0, acc[1][0]); MM16(a1, b1, acc[1][1]); MM16(a1, b2, acc[1][2]); MM16(a1, b3, acc[1][3]);
    MM16(a2, b0, acc[2][0]); MM16(a2, b1, acc[2][1]); MM16(a2, b2, acc[2][2]); MM16(a2, b3, acc[2][3]);
    MM16(a3, b0, acc[3][0]); MM16(a3, b1, acc[3][1]); MM16(a3, b2, acc[3][2]); MM16(a3, b3, acc[3][3]);
    __builtin_amdgcn_s_setprio(0);
    __builtin_amdgcn_s_barrier();

    // ---- phase 3: kh1, fi 4-7 ----
    a0 = RDA(c, 1, 4); a1 = RDA(c, 1, 5); a2 = RDA(c, 1, 6); a3 = RDA(c, 1, 7);
    if (st) STG(n, 3, kn + 32, BsL, BsH);
    __builtin_amdgcn_s_barrier();
    __builtin_amdgcn_s_setprio(1);
    MM16(a0, b0, acc[4][0]); MM16(a0, b1, acc[4][1]); MM16(a0, b2, acc[4][2]); MM16(a0, b3, acc[4][3]);
    MM16(a1, b0, acc[5][0]); MM16(a1, b1, acc[5][1]); MM16(a1, b2, acc[5][2]); MM16(a1, b3, acc[5][3]);
    MM16(a2, b0, acc[6][0]); MM16(a2, b1, acc[6][1]); MM16(a2, b2, acc[6][2]); MM16(a2, b3, acc[6][3]);
    MM16(a3, b0, acc[7][0]); MM16(a3, b1, acc[7][1]); MM16(a3, b2, acc[7][2]); MM16(a3, b3, acc[7][3]);
    __builtin_amdgcn_s_setprio(0);
    if (T + 1 < NT) {
      asm volatile("s_waitcnt vmcnt(4)" ::: "memory");  // next tile kh0 certified
      __builtin_amdgcn_s_barrier();
    }
  }

  // ---- epilogue ----
  const float qs = (EPI == 0 && col0 < E_) ? QSCL : 1.0f;  // tile col-uniform
#pragma unroll
  for (int fi = 0; fi < 8; ++fi) {
#pragma unroll
    for (int fj = 0; fj < 4; ++fj) {
      const int gr = row0 + wm * 128 + fi * 16 + l4 * 4;
      const int gc = col0 + wn * 64 + fj * 16 + l16;
      if (EPI == 0) {
        unsigned short* C = (unsigned short*)Cv;
#pragma unroll
        for (int r = 0; r < 4; ++r)
          C[(size_t)(gr + r) * N + gc] = f2bf(acc[fi][fj][r] * qs);
      } else {
        float* C = (float*)Cv;
        const float bv = bias[gc];
#pragma unroll
        for (int r = 0; r < 4; ++r)
          C[(size_t)(gr + r) * N + gc] = acc[fi][fj][r] + bv;
      }
    }
  }
}

// ---------- V columns of O1 -> Vt [bh][d][s] ----------
__global__ void k_vtrans(const unsigned short* __restrict__ O1, unsigned short* __restrict__ Vt) {
  __shared__ unsigned short t[64][66];
  const int st = blockIdx.x, bh = blockIdx.y;
  const int b = bh >> 4, h = bh & 15;
  const int tid = threadIdx.x;
  const int s0 = st * 64;
#pragma unroll
  for (int i = 0; i < 16; ++i) {
    int idx = tid + i * 256;
    int r = idx >> 6, d = idx & 63;
    t[r][d] = O1[(size_t)(b * S_ + s0 + r) * N1_ + 2 * E_ + h * 64 + d];
  }
  __syncthreads();
#pragma unroll
  for (int i = 0; i < 16; ++i) {
    int idx = tid + i * 256;
    int d = idx >> 6, j = idx & 63;
    Vt[(size_t)(bh * 64 + d) * S_ + s0 + j] = t[j][d];
  }
}

#define CVTPK(d, a, b) asm("v_cvt_pk_bf16_f32 %0, %1, %2" : "=v"(d) : "v"(a), "v"(b))
#define PLSWAP(x, y)   asm("v_permlane32_swap_b32 %0, %1" : "+v"(x), "+v"(y))

// ---------- fused causal flash attention, swapped-QK 32x32x16 ----------
__global__ __launch_bounds__(256, 3) void k_attn(
    const unsigned short* __restrict__ O1,  // [8192][3072]: Q|K|V (Q pre-scaled)
    const unsigned short* __restrict__ Vt,  // [64*64][2048]
    unsigned short* __restrict__ ctx) {     // [8192][1024]
  __shared__ __align__(16) short lK[2][64 * 64];   // XOR-swizzled, rows=kv
  __shared__ __align__(16) short lV[2][64 * 64];   // XOR-swizzled, rows=d
  __shared__ float lRS[4][32];

  const int idx = blockIdx.x;
  const int qi = 15 - (idx >> 6);     // heavy blocks dispatched first
  const int bh = idx & 63;
  const int b = bh >> 4, h = bh & 15;
  const int tid = threadIdx.x, wid = tid >> 6, lane = tid & 63;
  const int l31 = lane & 31, hi = lane >> 5;
  const int q0w = qi * 128 + wid * 32;

  bf16x8 qf[4];
#pragma unroll
  for (int s = 0; s < 4; ++s)
    qf[s] = *(const bf16x8*)&O1[(size_t)(b * S_ + q0w + l31) * N1_ + h * 64 + s * 16 + hi * 8];

  f32x16 acc[2] = {};
  float psum = 0.f;

  const int c0 = tid, c1 = tid + 256;
  const int r0c = c0 >> 3, o0c = (c0 & 7) * 8;
  const int r1c = c1 >> 3, o1c = (c1 & 7) * 8;
  const int ls0 = (r0c * 64 + o0c) ^ ((r0c & 7) << 3);
  const int ls1 = (r1c * 64 + o1c) ^ ((r1c & 7) << 3);

  const unsigned short* Kbase = O1 + (size_t)(b * S_) * N1_ + E_ + h * 64;
  const unsigned short* Vbase = Vt + (size_t)(bh * 64) * S_;

  const int ntiles = qi * 2 + 2;
  bf16x8 krA = *(const bf16x8*)&Kbase[(size_t)r0c * N1_ + o0c];
  bf16x8 krB = *(const bf16x8*)&Kbase[(size_t)r1c * N1_ + o1c];
  bf16x8 vrA = *(const bf16x8*)&Vbase[(size_t)r0c * S_ + o0c];
  bf16x8 vrB = *(const bf16x8*)&Vbase[(size_t)r1c * S_ + o1c];

  for (int t = 0; t < ntiles; ++t) {
    const int cur = t & 1;
    const int kv0 = t * 64;
    *(bf16x8*)&lK[cur][ls0] = krA;
    *(bf16x8*)&lK[cur][ls1] = krB;
    *(bf16x8*)&lV[cur][ls0] = vrA;
    *(bf16x8*)&lV[cur][ls1] = vrB;
    __syncthreads();
    if (t + 1 < ntiles) {
      const int kn = kv0 + 64;
      krA = *(const bf16x8*)&Kbase[(size_t)(kn + r0c) * N1_ + o0c];
      krB = *(const bf16x8*)&Kbase[(size_t)(kn + r1c) * N1_ + o1c];
      vrA = *(const bf16x8*)&Vbase[(size_t)r0c * S_ + kn + o0c];
      vrB = *(const bf16x8*)&Vbase[(size_t)r1c * S_ + kn + o1c];
    }

    if (kv0 <= q0w + 31) {
      __builtin_amdgcn_s_setprio(1);
      f32x16 s0 = {}, s1 = {};
#pragma unroll
      for (int s = 0; s < 4; ++s) {
        bf16x8 kf0 = *(const bf16x8*)&lK[cur][((l31) * 64 + s * 16 + hi * 8) ^ ((l31 & 7) << 3)];
        s0 = __builtin_amdgcn_mfma_f32_32x32x16_bf16(kf0, qf[s], s0, 0, 0, 0);
        bf16x8 kf1 = *(const bf16x8*)&lK[cur][((32 + l31) * 64 + s * 16 + hi * 8) ^ ((l31 & 7) << 3)];
        s1 = __builtin_amdgcn_mfma_f32_32x32x16_bf16(kf1, qf[s], s1, 0, 0, 0);
      }
      if (kv0 + 63 > q0w) {
        const int qg = q0w + l31;
#pragma unroll
        for (int r = 0; r < 16; ++r) {
          const int kv = kv0 + (r & 3) + 8 * (r >> 2) + 4 * hi;
          if (kv > qg) s0[r] = -1e30f;
          if (kv + 32 > qg) s1[r] = -1e30f;
        }
      }
#pragma unroll
      for (int r = 0; r < 16; ++r) {
        s0[r] = expraw(s0[r]);
        s1[r] = expraw(s1[r]);
        psum += s0[r] + s1[r];
      }
#pragma unroll
      for (int hh = 0; hh < 2; ++hh) {
        unsigned w0, w1, w2, w3, u0, u1, u2, u3;
        if (hh == 0) {
          CVTPK(w0, s0[0], s0[1]);  CVTPK(w2, s0[4], s0[5]);
          CVTPK(w1, s0[2], s0[3]);  CVTPK(w3, s0[6], s0[7]);
          CVTPK(u0, s0[8], s0[9]);  CVTPK(u2, s0[12], s0[13]);
          CVTPK(u1, s0[10], s0[11]); CVTPK(u3, s0[14], s0[15]);
        } else {
          CVTPK(w0, s1[0], s1[1]);  CVTPK(w2, s1[4], s1[5]);
          CVTPK(w1, s1[2], s1[3]);  CVTPK(w3, s1[6], s1[7]);
          CVTPK(u0, s1[8], s1[9]);  CVTPK(u2, s1[12], s1[13]);
          CVTPK(u1, s1[10], s1[11]); CVTPK(u3, s1[14], s1[15]);
        }
        PLSWAP(w0, w2); PLSWAP(w1, w3); PLSWAP(u0, u2); PLSWAP(u1, u3);
        union { unsigned w[4]; bf16x8 v; } paA, paB;
        paA.w[0] = w0; paA.w[1] = w1; paA.w[2] = w2; paA.w[3] = w3;
        paB.w[0] = u0; paB.w[1] = u1; paB.w[2] = u2; paB.w[3] = u3;
#pragma unroll
        for (int g = 0; g < 2; ++g) {
          bf16x8 vfA = *(const bf16x8*)&lV[cur][((g * 32 + l31) * 64 + hh * 32 + hi * 8) ^ ((l31 & 7) << 3)];
          acc[g] = __builtin_amdgcn_mfma_f32_32x32x16_bf16(paA.v, vfA, acc[g], 0, 0, 0);
          bf16x8 vfB = *(const bf16x8*)&lV[cur][((g * 32 + l31) * 64 + hh * 32 + 16 + hi * 8) ^ ((l31 & 7) << 3)];
          acc[g] = __builtin_amdgcn_mfma_f32_32x32x16_bf16(paB.v, vfB, acc[g], 0, 0, 0);
        }
      }
      __builtin_amdgcn_s_setprio(0);
    }
  }

  float rs = psum + __shfl_xor(psum, 32, 64);
  if (lane < 32) lRS[wid][l31] = rs;
  __syncthreads();

#pragma unroll
  for (int r = 0; r < 16; ++r) {
    const int cr = (r & 3) + 8 * (r >> 2) + 4 * hi;
    const float inv = 1.0f / lRS[wid][cr];
    const int q = q0w + cr;
#pragma unroll
    for (int g = 0; g < 2; ++g)
      ctx[(size_t)(b * S_ + q) * E_ + h * 64 + g * 32 + l31] = f2bf(acc[g][r] * inv);
  }
}

extern "C" void kernel_launch(void* const* d_in, const int* in_sizes, int n_in,
                              void* d_out, int out_size, void* d_ws, size_t ws_size,
                              hipStream_t stream) {
  const float* x  = (const float*)d_in[0];
  const float* Wq = (const float*)d_in[1];
  const float* Wk = (const float*)d_in[2];
  const float* Wv = (const float*)d_in[3];
  const float* Wp = (const float*)d_in[4];
  const float* bp = (const float*)d_in[5];
  float* out = (float*)d_out;

  char* ws = (char*)d_ws;
  unsigned short* xb  = (unsigned short*)(ws);             // 16 MiB (reused as ctx)
  unsigned short* Wt  = (unsigned short*)(ws + 16777216);  // 6 MiB
  unsigned short* Wpt = (unsigned short*)(ws + 23068672);  // 2 MiB
  unsigned short* O1  = (unsigned short*)(ws + 25165824);  // 48 MiB
  unsigned short* Vt  = (unsigned short*)(ws + 75497472);  // 16 MiB
  unsigned short* ctx = xb;  // xb dead after gemm1

  // 128 KiB dynamic LDS for both GEMM instantiations (set before capture; idempotent)
  (void)hipFuncSetAttribute((const void*)k_gemm256<0>,
                            hipFuncAttributeMaxDynamicSharedMemorySize, 131072);
  (void)hipFuncSetAttribute((const void*)k_gemm256<1>,
                            hipFuncAttributeMaxDynamicSharedMemorySize, 131072);

  k_cvt_x<<<2048, 256, 0, stream>>>(x, xb, (B_ * S_ * E_) / 4);
  k_wqkv_t<<<dim3(16, 16, 3), 256, 0, stream>>>(Wq, Wk, Wv, Wt);
  k_wp_t<<<dim3(16, 16), 256, 0, stream>>>(Wp, Wpt);
  k_gemm256<0><<<dim3(384), 512, 131072, stream>>>(xb, Wt, O1, nullptr, BS_, N1_, E_, 32);
  k_vtrans<<<dim3(32, 64), 256, 0, stream>>>(O1, Vt);
  k_attn<<<dim3(1024), 256, 0, stream>>>(O1, Vt, ctx);
  k_gemm256<1><<<dim3(128), 512, 131072, stream>>>(ctx, Wpt, out, bp, BS_, E_, E_, 32);
}